// Round 13
// baseline (462.786 us; speedup 1.0000x reference)
//
#include <hip/hip_runtime.h>
#include <hip/hip_bf16.h>
#include <stdint.h>

typedef __attribute__((ext_vector_type(8))) short s16x8;
typedef __attribute__((ext_vector_type(4))) float f32x4;
typedef __attribute__((ext_vector_type(16))) float f32x16;

#define QSCALE 0.045084220027780106f  // (1/32) * log2(e), folded into Q projection

__device__ __forceinline__ unsigned short f2bf(float f) {
    union { float f; uint32_t u; } v; v.f = f;
    uint32_t u = v.u;
    u += 0x7FFFu + ((u >> 16) & 1u);   // round-to-nearest-even
    return (unsigned short)(u >> 16);
}

__device__ __forceinline__ unsigned int pkbf2(float a, float b) {
    union { __hip_bfloat162 h; unsigned int u; } x;
    x.h = __float22bfloat162_rn(float2{a, b});
    return x.u;
}

#define GLOAD_LDS16(gptr, lptr)                                                         \
    __builtin_amdgcn_global_load_lds(                                                   \
        (const __attribute__((address_space(1))) unsigned int*)(gptr),                  \
        (__attribute__((address_space(3))) unsigned int*)(lptr), 16, 0, 0)

// ---------------- fused fp32 -> bf16 conversion (all 7 tensors, 1 launch) ----------
__global__ __launch_bounds__(256)
void cvt_all(const float* __restrict__ q, const float* __restrict__ k,
             const float* __restrict__ v, const float* __restrict__ wq,
             const float* __restrict__ wk, const float* __restrict__ wv,
             const float* __restrict__ wo,
             unsigned short* __restrict__ xq, unsigned short* __restrict__ xk,
             unsigned short* __restrict__ xv, unsigned short* __restrict__ wqb,
             unsigned short* __restrict__ wkb, unsigned short* __restrict__ wvb,
             unsigned short* __restrict__ wob)
{
    int bid = blockIdx.x;
    const float* src; unsigned short* dst; int rel;
    if (bid < 6144) {
        int s = bid >> 11; rel = bid & 2047;
        src = (s == 0) ? q : (s == 1) ? k : v;
        dst = (s == 0) ? xq : (s == 1) ? xk : xv;
    } else {
        int s = (bid - 6144) >> 9; rel = (bid - 6144) & 511;
        src = (s == 0) ? wq : (s == 1) ? wk : (s == 2) ? wv : wo;
        dst = (s == 0) ? wqb : (s == 1) ? wkb : (s == 2) ? wvb : wob;
    }
    size_t i = (size_t)rel * 256 + threadIdx.x;
    const float4* p = (const float4*)src;
    float4 a = p[i * 2];
    float4 b2 = p[i * 2 + 1];
    s16x8 r;
    r[0] = (short)f2bf(a.x);  r[1] = (short)f2bf(a.y);
    r[2] = (short)f2bf(a.z);  r[3] = (short)f2bf(a.w);
    r[4] = (short)f2bf(b2.x); r[5] = (short)f2bf(b2.y);
    r[6] = (short)f2bf(b2.z); r[7] = (short)f2bf(b2.w);
    *(s16x8*)(dst + i * 8) = r;
}

// ---------------- NT GEMM, 512 threads / 8 waves (2M x 4N): C = A * Bt^T ------------
// mode 0: bf16 C (scaled); mode 1: f32 C; mode 2: Vt transposed write via LDS.
__device__ __forceinline__ void gemm_tile512(const unsigned short* __restrict__ A,
                                             const unsigned short* __restrict__ Bt,
                                             void* __restrict__ C,
                                             int N, int K, int mode, float cscale,
                                             unsigned short* Al, unsigned short* Bl,
                                             unsigned short* Tl)
{
    const int tid  = threadIdx.x;
    const int lane = tid & 63;
    const int w    = tid >> 6;          // 0..7
    const int wr   = w >> 2, wc = w & 3;
    const int l15  = lane & 15, l4 = lane >> 4;

    const int m0 = blockIdx.x * 128;
    const int n0 = blockIdx.y * 128;

    f32x4 acc[4][2];
#pragma unroll
    for (int i = 0; i < 4; ++i)
#pragma unroll
        for (int j = 0; j < 2; ++j) acc[i][j] = (f32x4){0.f, 0.f, 0.f, 0.f};

    const int slin = w * 64 + lane;
    const int srow = slin >> 2;
    const int scol = ((slin & 3) ^ ((srow >> 1) & 3)) * 8;

    int aoff[4], boff[2];
#pragma unroll
    for (int mi = 0; mi < 4; ++mi) {
        int rowa = wr * 64 + mi * 16 + l15;
        aoff[mi] = rowa * 32 + ((l4 ^ ((rowa >> 1) & 3)) * 8);
    }
#pragma unroll
    for (int nf = 0; nf < 2; ++nf) {
        int rowb = wc * 32 + nf * 16 + l15;
        boff[nf] = rowb * 32 + ((l4 ^ ((rowb >> 1) & 3)) * 8);
    }

    for (int k0 = 0; k0 < K; k0 += 32) {
        {
            const unsigned short* gA = A + (size_t)(m0 + srow) * K + k0 + scol;
            GLOAD_LDS16(gA, Al + w * 512);
            const unsigned short* gB = Bt + (size_t)(n0 + srow) * K + k0 + scol;
            GLOAD_LDS16(gB, Bl + w * 512);
        }
        __syncthreads();
        s16x8 af[4], bfr[2];
#pragma unroll
        for (int mi = 0; mi < 4; ++mi) af[mi] = *(const s16x8*)(Al + aoff[mi]);
#pragma unroll
        for (int nf = 0; nf < 2; ++nf) bfr[nf] = *(const s16x8*)(Bl + boff[nf]);
#pragma unroll
        for (int mi = 0; mi < 4; ++mi)
#pragma unroll
            for (int nf = 0; nf < 2; ++nf)
                acc[mi][nf] = __builtin_amdgcn_mfma_f32_16x16x32_bf16(af[mi], bfr[nf], acc[mi][nf], 0, 0, 0);
        __syncthreads();
    }

    if (mode == 2) {
        const int b_  = m0 >> 11;
        const int s0g = m0 & 2047;
#pragma unroll
        for (int c0 = 0; c0 < 128; c0 += 32) {
            if (wc == (c0 >> 5)) {
#pragma unroll
                for (int mi = 0; mi < 4; ++mi)
#pragma unroll
                    for (int nf = 0; nf < 2; ++nf) {
                        uint2 pw;
                        pw.x = pkbf2(acc[mi][nf][0], acc[mi][nf][1]);
                        pw.y = pkbf2(acc[mi][nf][2], acc[mi][nf][3]);
                        int c  = nf * 16 + l15;
                        int s4 = wr * 64 + mi * 16 + l4 * 4;
                        *(uint2*)&Tl[c * 136 + s4] = pw;
                    }
            }
            __syncthreads();
            {
                int d  = tid >> 4;          // 0..31
                int sg = tid & 15;
                s16x8 v = *(const s16x8*)&Tl[d * 136 + sg * 8];
                int colg  = n0 + c0 + d;
                int vtrow = (b_ * 16 + (colg >> 6)) * 64 + (colg & 63);
                *(s16x8*)((unsigned short*)C + (size_t)vtrow * 2048 + s0g + sg * 8) = v;
            }
            __syncthreads();
        }
        return;
    }

#pragma unroll
    for (int mi = 0; mi < 4; ++mi)
#pragma unroll
        for (int nf = 0; nf < 2; ++nf)
#pragma unroll
            for (int r = 0; r < 4; ++r) {
                int row = m0 + wr * 64 + mi * 16 + l4 * 4 + r;
                int col = n0 + wc * 32 + nf * 16 + l15;
                float v = acc[mi][nf][r];
                if (mode == 1) ((float*)C)[(size_t)row * N + col] = v;
                else           ((unsigned short*)C)[(size_t)row * N + col] = f2bf(v * cscale);
            }
}

__global__ __launch_bounds__(512, 6)
void gemm_qkv(const unsigned short* __restrict__ A0, const unsigned short* __restrict__ A1,
              const unsigned short* __restrict__ A2,
              const unsigned short* __restrict__ B0, const unsigned short* __restrict__ B1,
              const unsigned short* __restrict__ B2,
              unsigned short* __restrict__ C0, unsigned short* __restrict__ C1,
              unsigned short* __restrict__ C2)
{
    __shared__ unsigned short Al[128 * 32];
    __shared__ unsigned short Bl[128 * 32];
    __shared__ unsigned short Tl[32 * 136];
    int z = blockIdx.z;
    const unsigned short* A  = (z == 0) ? A0 : (z == 1) ? A1 : A2;
    const unsigned short* Bt = (z == 0) ? B0 : (z == 1) ? B1 : B2;
    unsigned short*       C  = (z == 0) ? C0 : (z == 1) ? C1 : C2;
    float cscale = (z == 0) ? QSCALE : 1.0f;
    int mode = (z == 2) ? 2 : 0;    // V projection writes Vt (transposed, coalesced)
    gemm_tile512(A, Bt, C, 1024, 1024, mode, cscale, Al, Bl, Tl);
}

// ---------------- gemm_out: 128x64 tiles, 2 blocks/CU (16 waves/CU) ----------------
__global__ __launch_bounds__(512, 4)
void gemm_out64(const unsigned short* __restrict__ A, const unsigned short* __restrict__ Bt,
                float* __restrict__ C)
{
    __shared__ unsigned short Al[128 * 32];   // 8 KB
    __shared__ unsigned short Bl[64 * 32];    // 4 KB

    const int tid  = threadIdx.x;
    const int lane = tid & 63;
    const int w    = tid >> 6;          // 0..7
    const int wr   = w >> 1, wc = w & 1;
    const int l15  = lane & 15, l4 = lane >> 4;

    const int m0 = blockIdx.x * 128;
    const int n0 = blockIdx.y * 64;
    const int N = 1024, K = 1024;

    f32x4 acc[2][2];
#pragma unroll
    for (int i = 0; i < 2; ++i)
#pragma unroll
        for (int j = 0; j < 2; ++j) acc[i][j] = (f32x4){0.f, 0.f, 0.f, 0.f};

    const int slin = w * 64 + lane;           // A: 512 granules
    const int srow = slin >> 2;
    const int scol = ((slin & 3) ^ ((srow >> 1) & 3)) * 8;
    const int brow = (w < 4) ? (slin >> 2) : 0;   // B: 256 granules (waves 0-3)
    const int bcol = ((slin & 3) ^ ((brow >> 1) & 3)) * 8;

    int aoff[2], boff[2];
#pragma unroll
    for (int mi = 0; mi < 2; ++mi) {
        int rowa = wr * 32 + mi * 16 + l15;
        aoff[mi] = rowa * 32 + ((l4 ^ ((rowa >> 1) & 3)) * 8);
    }
#pragma unroll
    for (int nf = 0; nf < 2; ++nf) {
        int rowb = wc * 32 + nf * 16 + l15;
        boff[nf] = rowb * 32 + ((l4 ^ ((rowb >> 1) & 3)) * 8);
    }

    for (int k0 = 0; k0 < K; k0 += 32) {
        {
            const unsigned short* gA = A + (size_t)(m0 + srow) * K + k0 + scol;
            GLOAD_LDS16(gA, Al + w * 512);
            if (w < 4) {
                const unsigned short* gB = Bt + (size_t)(n0 + brow) * K + k0 + bcol;
                GLOAD_LDS16(gB, Bl + w * 512);
            }
        }
        __syncthreads();
        s16x8 af[2], bfr[2];
#pragma unroll
        for (int mi = 0; mi < 2; ++mi) af[mi] = *(const s16x8*)(Al + aoff[mi]);
#pragma unroll
        for (int nf = 0; nf < 2; ++nf) bfr[nf] = *(const s16x8*)(Bl + boff[nf]);
#pragma unroll
        for (int mi = 0; mi < 2; ++mi)
#pragma unroll
            for (int nf = 0; nf < 2; ++nf)
                acc[mi][nf] = __builtin_amdgcn_mfma_f32_16x16x32_bf16(af[mi], bfr[nf], acc[mi][nf], 0, 0, 0);
        __syncthreads();
    }

#pragma unroll
    for (int mi = 0; mi < 2; ++mi)
#pragma unroll
        for (int nf = 0; nf < 2; ++nf)
#pragma unroll
            for (int r = 0; r < 4; ++r) {
                int row = m0 + wr * 32 + mi * 16 + l4 * 4 + r;
                int col = n0 + wc * 32 + nf * 16 + l15;
                C[(size_t)row * N + col] = acc[mi][nf][r];
            }
}

// ---------------- flash attention v9: NO LDS staging -- K/V fragments from L2 -------
// 1024 blocks x 512 threads = 8 waves = 4 KV-quarters x 2 sub-waves; 64 q-rows/block.
// K/V per (b,h) = 512 KB; 4 bh per XCD -> L2-resident (lesson m169: don't stage what
// L2-fits). No loop barriers, no bank conflicts; 32 waves/CU hides L2 latency.
__global__ __launch_bounds__(512, 8)
void attn9(const unsigned short* __restrict__ Q,
           const unsigned short* __restrict__ Kp,
           const unsigned short* __restrict__ Vt,
           unsigned short* __restrict__ O)
{
    __shared__ f32x4 Xch[4 * 8 * 64];   // 32 KB merge buffer
    __shared__ float Lx[4][32];

    const int tid  = threadIdx.x;
    const int lane = tid & 63;
    const int w    = tid >> 6;
    const int quarter = w >> 1, sub = w & 1;
    const int q31  = lane & 31;
    const int lh   = lane >> 5;

    // 1024 blocks: 8 XCDs x 4 bh x 32 q-tiles; consecutive ids share bh (L1/L2 reuse)
    const int hw  = blockIdx.x;
    const int xcd = hw & 7;
    const int idx = hw >> 3;            // 0..127
    const int bh  = xcd * 4 + (idx >> 5);
    const int qt  = idx & 31;           // 64-row q tile
    const int b = bh >> 4, hd = bh & 15;
    const int colbase = hd * 64;
    const int kvbase = quarter * 512;

    const size_t qrow = (size_t)(b * 2048 + qt * 64 + sub * 32 + q31);
    s16x8 qf[4];
#pragma unroll
    for (int dk = 0; dk < 4; ++dk)
        qf[dk] = *(const s16x8*)(Q + qrow * 1024 + colbase + dk * 16 + lh * 8);

    f32x16 oa[2] = {};
    float l_run = 0.f;

    for (int kt = 0; kt < 8; ++kt) {
        const int kv0 = kvbase + kt * 64;
        const unsigned short* Kb = Kp + (size_t)(b * 2048 + kv0 + q31) * 1024 + colbase + lh * 8;
        const unsigned short* Vb = Vt + ((size_t)bh * 64 + q31) * 2048 + kv0 + lh * 8;

        // ---- QK^T: S^T[key][q] straight from L2
        f32x16 s0 = {}, s1 = {};
#pragma unroll
        for (int dk = 0; dk < 4; ++dk) {
            s16x8 kf0 = *(const s16x8*)(Kb + dk * 16);
            s16x8 kf1 = *(const s16x8*)(Kb + 32 * 1024 + dk * 16);
            s0 = __builtin_amdgcn_mfma_f32_32x32x16_bf16(kf0, qf[dk], s0, 0, 0, 0);
            s1 = __builtin_amdgcn_mfma_f32_32x32x16_bf16(kf1, qf[dk], s1, 0, 0, 0);
        }

        // ---- softmax numerator (no max-sub), pack to bf16 pairs in-register
        unsigned int PK[2][8];
        float ps = 0.f;
        {
            float p[16];
#pragma unroll
            for (int i = 0; i < 16; ++i) { p[i] = __builtin_amdgcn_exp2f(s0[i]); ps += p[i]; }
#pragma unroll
            for (int j = 0; j < 8; ++j) PK[0][j] = pkbf2(p[2 * j], p[2 * j + 1]);
#pragma unroll
            for (int i = 0; i < 16; ++i) { p[i] = __builtin_amdgcn_exp2f(s1[i]); ps += p[i]; }
#pragma unroll
            for (int j = 0; j < 8; ++j) PK[1][j] = pkbf2(p[2 * j], p[2 * j + 1]);
        }
        l_run += ps;

        // ---- PV: P B-frag via shfl_xor(32)+select (R9-verified); V frags from L2
#pragma unroll
        for (int t = 0; t < 4; ++t) {
            const int bk = t >> 1, j0 = (t & 1) * 4;
            unsigned int A0 = PK[bk][j0],     C0 = PK[bk][j0 + 2];
            unsigned int A1 = PK[bk][j0 + 1], C1 = PK[bk][j0 + 3];
            unsigned int sA0 = (unsigned int)__shfl_xor((int)A0, 32, 64);
            unsigned int sC0 = (unsigned int)__shfl_xor((int)C0, 32, 64);
            unsigned int sA1 = (unsigned int)__shfl_xor((int)A1, 32, 64);
            unsigned int sC1 = (unsigned int)__shfl_xor((int)C1, 32, 64);
            union { unsigned int u[4]; s16x8 v; } pa;
            pa.u[0] = lh ? sC0 : A0;
            pa.u[1] = lh ? sC1 : A1;
            pa.u[2] = lh ? C0 : sA0;
            pa.u[3] = lh ? C1 : sA1;
            s16x8 vf0 = *(const s16x8*)(Vb + t * 16);
            s16x8 vf1 = *(const s16x8*)(Vb + 32 * 2048 + t * 16);
            oa[0] = __builtin_amdgcn_mfma_f32_32x32x16_bf16(vf0, pa.v, oa[0], 0, 0, 0);
            oa[1] = __builtin_amdgcn_mfma_f32_32x32x16_bf16(vf1, pa.v, oa[1], 0, 0, 0);
        }
    }

    // ---- merge: 4 quarter-partials, linear combine (tree via LDS, 3 barriers)
    l_run += __shfl_xor(l_run, 32, 64);

    // round 1: quarters 2,3 publish; quarters 0,1 add
    if (w >= 4) {
        int wrel = w - 4;
#pragma unroll
        for (int dh = 0; dh < 2; ++dh)
#pragma unroll
            for (int rg = 0; rg < 4; ++rg) {
                f32x4 c = { oa[dh][rg * 4 + 0], oa[dh][rg * 4 + 1],
                            oa[dh][rg * 4 + 2], oa[dh][rg * 4 + 3] };
                Xch[((wrel * 8 + dh * 4 + rg) << 6) + lane] = c;
            }
        if (lh == 0) Lx[wrel][q31] = l_run;
    }
    __syncthreads();
    if (w < 4) {
#pragma unroll
        for (int dh = 0; dh < 2; ++dh)
#pragma unroll
            for (int rg = 0; rg < 4; ++rg) {
                f32x4 po = Xch[((w * 8 + dh * 4 + rg) << 6) + lane];
                oa[dh][rg * 4 + 0] += po[0]; oa[dh][rg * 4 + 1] += po[1];
                oa[dh][rg * 4 + 2] += po[2]; oa[dh][rg * 4 + 3] += po[3];
            }
        l_run += Lx[w][q31];
    }
    __syncthreads();
    // round 2: quarter 1 publishes; quarter 0 adds + stores
    if (w == 2 || w == 3) {
        int wrel = w - 2;
#pragma unroll
        for (int dh = 0; dh < 2; ++dh)
#pragma unroll
            for (int rg = 0; rg < 4; ++rg) {
                f32x4 c = { oa[dh][rg * 4 + 0], oa[dh][rg * 4 + 1],
                            oa[dh][rg * 4 + 2], oa[dh][rg * 4 + 3] };
                Xch[((wrel * 8 + dh * 4 + rg) << 6) + lane] = c;
            }
        if (lh == 0) Lx[wrel][q31] = l_run;
    }
    __syncthreads();
    if (w < 2) {
        const float lt  = l_run + Lx[w][q31];
        const float inv = 1.0f / lt;
#pragma unroll
        for (int dh = 0; dh < 2; ++dh)
#pragma unroll
            for (int rg = 0; rg < 4; ++rg) {
                f32x4 po = Xch[((w * 8 + dh * 4 + rg) << 6) + lane];
                const int d0 = dh * 32 + rg * 8 + lh * 4;
                uint2 pw;
                pw.x = pkbf2((oa[dh][rg * 4 + 0] + po[0]) * inv,
                             (oa[dh][rg * 4 + 1] + po[1]) * inv);
                pw.y = pkbf2((oa[dh][rg * 4 + 2] + po[2]) * inv,
                             (oa[dh][rg * 4 + 3] + po[3]) * inv);
                *(uint2*)(O + qrow * 1024 + colbase + d0) = pw;
            }
    }
}

// ---------------- launch ----------------
extern "C" void kernel_launch(void* const* d_in, const int* in_sizes, int n_in,
                              void* d_out, int out_size, void* d_ws, size_t ws_size,
                              hipStream_t stream)
{
    const float* query = (const float*)d_in[0];
    const float* key   = (const float*)d_in[1];
    const float* value = (const float*)d_in[2];
    const float* Wq    = (const float*)d_in[3];
    const float* Wk    = (const float*)d_in[4];
    const float* Wv    = (const float*)d_in[5];
    const float* Wo    = (const float*)d_in[6];
    float* out = (float*)d_out;

    char* ws = (char*)d_ws;
    const size_t SZX = (size_t)4096 * 1024 * 2;  // 8 MiB
    const size_t SZW = (size_t)1024 * 1024 * 2;  // 2 MiB
    unsigned short* Xq  = (unsigned short*)(ws + 0);
    unsigned short* Xk  = (unsigned short*)(ws + SZX);
    unsigned short* Xv  = (unsigned short*)(ws + 2 * SZX);
    unsigned short* Wqb = (unsigned short*)(ws + 3 * SZX);
    unsigned short* Wkb = (unsigned short*)(ws + 3 * SZX + SZW);
    unsigned short* Wvb = (unsigned short*)(ws + 3 * SZX + 2 * SZW);
    unsigned short* Wob = (unsigned short*)(ws + 3 * SZX + 3 * SZW);
    unsigned short* Pq  = (unsigned short*)(ws + 3 * SZX + 4 * SZW);
    unsigned short* Pk  = (unsigned short*)(ws + 4 * SZX + 4 * SZW);
    unsigned short* Vt  = (unsigned short*)(ws + 5 * SZX + 4 * SZW);  // transposed V
    unsigned short* AO  = (unsigned short*)(ws + 6 * SZX + 4 * SZW);

    cvt_all<<<8192, 256, 0, stream>>>(query, key, value, Wq, Wk, Wv, Wo,
                                      Xq, Xk, Xv, Wqb, Wkb, Wvb, Wob);
    gemm_qkv<<<dim3(32, 8, 3), 512, 0, stream>>>(Xq, Xk, Xv, Wqb, Wkb, Wvb, Pq, Pk, Vt);
    attn9<<<1024, 512, 0, stream>>>(Pq, Pk, Vt, AO);
    gemm_out64<<<dim3(32, 16), 512, 0, stream>>>(AO, Wob, out);
}

// Round 16
// 189.871 us; speedup vs baseline: 2.4374x; 2.4374x over previous
//
#include <hip/hip_runtime.h>
#include <hip/hip_bf16.h>
#include <stdint.h>

typedef __attribute__((ext_vector_type(8))) short s16x8;
typedef __attribute__((ext_vector_type(4))) float f32x4;
typedef __attribute__((ext_vector_type(16))) float f32x16;

#define QSCALE 0.045084220027780106f  // (1/32) * log2(e), folded into Q projection

__device__ __forceinline__ unsigned short f2bf(float f) {
    union { float f; uint32_t u; } v; v.f = f;
    uint32_t u = v.u;
    u += 0x7FFFu + ((u >> 16) & 1u);   // round-to-nearest-even
    return (unsigned short)(u >> 16);
}

__device__ __forceinline__ unsigned int pkbf2(float a, float b) {
    union { __hip_bfloat162 h; unsigned int u; } x;
    x.h = __float22bfloat162_rn(float2{a, b});
    return x.u;
}

#define GLOAD_LDS16(gptr, lptr)                                                         \
    __builtin_amdgcn_global_load_lds(                                                   \
        (const __attribute__((address_space(1))) unsigned int*)(gptr),                  \
        (__attribute__((address_space(3))) unsigned int*)(lptr), 16, 0, 0)

// ---------------- fused fp32 -> bf16 conversion (all 7 tensors, 1 launch) ----------
__global__ __launch_bounds__(256)
void cvt_all(const float* __restrict__ q, const float* __restrict__ k,
             const float* __restrict__ v, const float* __restrict__ wq,
             const float* __restrict__ wk, const float* __restrict__ wv,
             const float* __restrict__ wo,
             unsigned short* __restrict__ xq, unsigned short* __restrict__ xk,
             unsigned short* __restrict__ xv, unsigned short* __restrict__ wqb,
             unsigned short* __restrict__ wkb, unsigned short* __restrict__ wvb,
             unsigned short* __restrict__ wob)
{
    int bid = blockIdx.x;
    const float* src; unsigned short* dst; int rel;
    if (bid < 6144) {
        int s = bid >> 11; rel = bid & 2047;
        src = (s == 0) ? q : (s == 1) ? k : v;
        dst = (s == 0) ? xq : (s == 1) ? xk : xv;
    } else {
        int s = (bid - 6144) >> 9; rel = (bid - 6144) & 511;
        src = (s == 0) ? wq : (s == 1) ? wk : (s == 2) ? wv : wo;
        dst = (s == 0) ? wqb : (s == 1) ? wkb : (s == 2) ? wvb : wob;
    }
    size_t i = (size_t)rel * 256 + threadIdx.x;
    const float4* p = (const float4*)src;
    float4 a = p[i * 2];
    float4 b2 = p[i * 2 + 1];
    s16x8 r;
    r[0] = (short)f2bf(a.x);  r[1] = (short)f2bf(a.y);
    r[2] = (short)f2bf(a.z);  r[3] = (short)f2bf(a.w);
    r[4] = (short)f2bf(b2.x); r[5] = (short)f2bf(b2.y);
    r[6] = (short)f2bf(b2.z); r[7] = (short)f2bf(b2.w);
    *(s16x8*)(dst + i * 8) = r;
}

// ---------------- NT GEMM, 512 threads / 8 waves (2M x 4N): C = A * Bt^T ------------
// mode 0: bf16 C (scaled); mode 1: f32 C; mode 2: Vt transposed write via LDS.
__device__ __forceinline__ void gemm_tile512(const unsigned short* __restrict__ A,
                                             const unsigned short* __restrict__ Bt,
                                             void* __restrict__ C,
                                             int N, int K, int mode, float cscale,
                                             unsigned short* Al, unsigned short* Bl,
                                             unsigned short* Tl)
{
    const int tid  = threadIdx.x;
    const int lane = tid & 63;
    const int w    = tid >> 6;          // 0..7
    const int wr   = w >> 2, wc = w & 3;
    const int l15  = lane & 15, l4 = lane >> 4;

    const int m0 = blockIdx.x * 128;
    const int n0 = blockIdx.y * 128;

    f32x4 acc[4][2];
#pragma unroll
    for (int i = 0; i < 4; ++i)
#pragma unroll
        for (int j = 0; j < 2; ++j) acc[i][j] = (f32x4){0.f, 0.f, 0.f, 0.f};

    const int slin = w * 64 + lane;
    const int srow = slin >> 2;
    const int scol = ((slin & 3) ^ ((srow >> 1) & 3)) * 8;

    int aoff[4], boff[2];
#pragma unroll
    for (int mi = 0; mi < 4; ++mi) {
        int rowa = wr * 64 + mi * 16 + l15;
        aoff[mi] = rowa * 32 + ((l4 ^ ((rowa >> 1) & 3)) * 8);
    }
#pragma unroll
    for (int nf = 0; nf < 2; ++nf) {
        int rowb = wc * 32 + nf * 16 + l15;
        boff[nf] = rowb * 32 + ((l4 ^ ((rowb >> 1) & 3)) * 8);
    }

    for (int k0 = 0; k0 < K; k0 += 32) {
        {
            const unsigned short* gA = A + (size_t)(m0 + srow) * K + k0 + scol;
            GLOAD_LDS16(gA, Al + w * 512);
            const unsigned short* gB = Bt + (size_t)(n0 + srow) * K + k0 + scol;
            GLOAD_LDS16(gB, Bl + w * 512);
        }
        __syncthreads();
        s16x8 af[4], bfr[2];
#pragma unroll
        for (int mi = 0; mi < 4; ++mi) af[mi] = *(const s16x8*)(Al + aoff[mi]);
#pragma unroll
        for (int nf = 0; nf < 2; ++nf) bfr[nf] = *(const s16x8*)(Bl + boff[nf]);
#pragma unroll
        for (int mi = 0; mi < 4; ++mi)
#pragma unroll
            for (int nf = 0; nf < 2; ++nf)
                acc[mi][nf] = __builtin_amdgcn_mfma_f32_16x16x32_bf16(af[mi], bfr[nf], acc[mi][nf], 0, 0, 0);
        __syncthreads();
    }

    if (mode == 2) {
        const int b_  = m0 >> 11;
        const int s0g = m0 & 2047;
#pragma unroll
        for (int c0 = 0; c0 < 128; c0 += 32) {
            if (wc == (c0 >> 5)) {
#pragma unroll
                for (int mi = 0; mi < 4; ++mi)
#pragma unroll
                    for (int nf = 0; nf < 2; ++nf) {
                        uint2 pw;
                        pw.x = pkbf2(acc[mi][nf][0], acc[mi][nf][1]);
                        pw.y = pkbf2(acc[mi][nf][2], acc[mi][nf][3]);
                        int c  = nf * 16 + l15;
                        int s4 = wr * 64 + mi * 16 + l4 * 4;
                        *(uint2*)&Tl[c * 136 + s4] = pw;
                    }
            }
            __syncthreads();
            {
                int d  = tid >> 4;          // 0..31
                int sg = tid & 15;
                s16x8 v = *(const s16x8*)&Tl[d * 136 + sg * 8];
                int colg  = n0 + c0 + d;
                int vtrow = (b_ * 16 + (colg >> 6)) * 64 + (colg & 63);
                *(s16x8*)((unsigned short*)C + (size_t)vtrow * 2048 + s0g + sg * 8) = v;
            }
            __syncthreads();
        }
        return;
    }

#pragma unroll
    for (int mi = 0; mi < 4; ++mi)
#pragma unroll
        for (int nf = 0; nf < 2; ++nf)
#pragma unroll
            for (int r = 0; r < 4; ++r) {
                int row = m0 + wr * 64 + mi * 16 + l4 * 4 + r;
                int col = n0 + wc * 32 + nf * 16 + l15;
                float v = acc[mi][nf][r];
                if (mode == 1) ((float*)C)[(size_t)row * N + col] = v;
                else           ((unsigned short*)C)[(size_t)row * N + col] = f2bf(v * cscale);
            }
}

__global__ __launch_bounds__(512, 6)
void gemm_qkv(const unsigned short* __restrict__ A0, const unsigned short* __restrict__ A1,
              const unsigned short* __restrict__ A2,
              const unsigned short* __restrict__ B0, const unsigned short* __restrict__ B1,
              const unsigned short* __restrict__ B2,
              unsigned short* __restrict__ C0, unsigned short* __restrict__ C1,
              unsigned short* __restrict__ C2)
{
    __shared__ unsigned short Al[128 * 32];
    __shared__ unsigned short Bl[128 * 32];
    __shared__ unsigned short Tl[32 * 136];
    int z = blockIdx.z;
    const unsigned short* A  = (z == 0) ? A0 : (z == 1) ? A1 : A2;
    const unsigned short* Bt = (z == 0) ? B0 : (z == 1) ? B1 : B2;
    unsigned short*       C  = (z == 0) ? C0 : (z == 1) ? C1 : C2;
    float cscale = (z == 0) ? QSCALE : 1.0f;
    int mode = (z == 2) ? 2 : 0;    // V projection writes Vt (transposed, coalesced)
    gemm_tile512(A, Bt, C, 1024, 1024, mode, cscale, Al, Bl, Tl);
}

// ---------------- gemm_out: 128x64 tiles, 2 blocks/CU (16 waves/CU) ----------------
__global__ __launch_bounds__(512, 4)
void gemm_out64(const unsigned short* __restrict__ A, const unsigned short* __restrict__ Bt,
                float* __restrict__ C)
{
    __shared__ unsigned short Al[128 * 32];   // 8 KB
    __shared__ unsigned short Bl[64 * 32];    // 4 KB

    const int tid  = threadIdx.x;
    const int lane = tid & 63;
    const int w    = tid >> 6;          // 0..7
    const int wr   = w >> 1, wc = w & 1;
    const int l15  = lane & 15, l4 = lane >> 4;

    const int m0 = blockIdx.x * 128;
    const int n0 = blockIdx.y * 64;
    const int N = 1024, K = 1024;

    f32x4 acc[2][2];
#pragma unroll
    for (int i = 0; i < 2; ++i)
#pragma unroll
        for (int j = 0; j < 2; ++j) acc[i][j] = (f32x4){0.f, 0.f, 0.f, 0.f};

    const int slin = w * 64 + lane;           // A: 512 granules
    const int srow = slin >> 2;
    const int scol = ((slin & 3) ^ ((srow >> 1) & 3)) * 8;
    const int brow = (w < 4) ? (slin >> 2) : 0;   // B: 256 granules (waves 0-3)
    const int bcol = ((slin & 3) ^ ((brow >> 1) & 3)) * 8;

    int aoff[2], boff[2];
#pragma unroll
    for (int mi = 0; mi < 2; ++mi) {
        int rowa = wr * 32 + mi * 16 + l15;
        aoff[mi] = rowa * 32 + ((l4 ^ ((rowa >> 1) & 3)) * 8);
    }
#pragma unroll
    for (int nf = 0; nf < 2; ++nf) {
        int rowb = wc * 32 + nf * 16 + l15;
        boff[nf] = rowb * 32 + ((l4 ^ ((rowb >> 1) & 3)) * 8);
    }

    for (int k0 = 0; k0 < K; k0 += 32) {
        {
            const unsigned short* gA = A + (size_t)(m0 + srow) * K + k0 + scol;
            GLOAD_LDS16(gA, Al + w * 512);
            if (w < 4) {
                const unsigned short* gB = Bt + (size_t)(n0 + brow) * K + k0 + bcol;
                GLOAD_LDS16(gB, Bl + w * 512);
            }
        }
        __syncthreads();
        s16x8 af[2], bfr[2];
#pragma unroll
        for (int mi = 0; mi < 2; ++mi) af[mi] = *(const s16x8*)(Al + aoff[mi]);
#pragma unroll
        for (int nf = 0; nf < 2; ++nf) bfr[nf] = *(const s16x8*)(Bl + boff[nf]);
#pragma unroll
        for (int mi = 0; mi < 2; ++mi)
#pragma unroll
            for (int nf = 0; nf < 2; ++nf)
                acc[mi][nf] = __builtin_amdgcn_mfma_f32_16x16x32_bf16(af[mi], bfr[nf], acc[mi][nf], 0, 0, 0);
        __syncthreads();
    }

#pragma unroll
    for (int mi = 0; mi < 2; ++mi)
#pragma unroll
        for (int nf = 0; nf < 2; ++nf)
#pragma unroll
            for (int r = 0; r < 4; ++r) {
                int row = m0 + wr * 32 + mi * 16 + l4 * 4 + r;
                int col = n0 + wc * 32 + nf * 16 + l15;
                C[(size_t)row * N + col] = acc[mi][nf][r];
            }
}

// ---------------- flash attention v9b: L2-direct K/V, launch_bounds(512,4) ----------
// R13 failed via VGPR spill from the (512,8) cap, not the memory path. Same kernel at
// (512,4): 128-VGPR budget (no spill), 16 waves/CU, no loop barriers / staging /
// bank conflicts. Sub-wave pairs read identical K/V addresses -> L1 reuse.
__global__ __launch_bounds__(512, 4)
void attn9(const unsigned short* __restrict__ Q,
           const unsigned short* __restrict__ Kp,
           const unsigned short* __restrict__ Vt,
           unsigned short* __restrict__ O)
{
    __shared__ f32x4 Xch[4 * 8 * 64];   // 32 KB merge buffer
    __shared__ float Lx[4][32];

    const int tid  = threadIdx.x;
    const int lane = tid & 63;
    const int w    = tid >> 6;
    const int quarter = w >> 1, sub = w & 1;
    const int q31  = lane & 31;
    const int lh   = lane >> 5;

    const int hw  = blockIdx.x;
    const int xcd = hw & 7;
    const int idx = hw >> 3;            // 0..127
    const int bh  = xcd * 4 + (idx >> 5);
    const int qt  = idx & 31;           // 64-row q tile
    const int b = bh >> 4, hd = bh & 15;
    const int colbase = hd * 64;
    const int kvbase = quarter * 512;

    const size_t qrow = (size_t)(b * 2048 + qt * 64 + sub * 32 + q31);
    s16x8 qf[4];
#pragma unroll
    for (int dk = 0; dk < 4; ++dk)
        qf[dk] = *(const s16x8*)(Q + qrow * 1024 + colbase + dk * 16 + lh * 8);

    f32x16 oa[2] = {};
    float l_run = 0.f;

    for (int kt = 0; kt < 8; ++kt) {
        const int kv0 = kvbase + kt * 64;
        const unsigned short* Kb = Kp + (size_t)(b * 2048 + kv0 + q31) * 1024 + colbase + lh * 8;
        const unsigned short* Vb = Vt + ((size_t)bh * 64 + q31) * 2048 + kv0 + lh * 8;

        // ---- QK^T: S^T[key][q] straight from L2
        f32x16 s0 = {}, s1 = {};
#pragma unroll
        for (int dk = 0; dk < 4; ++dk) {
            s16x8 kf0 = *(const s16x8*)(Kb + dk * 16);
            s16x8 kf1 = *(const s16x8*)(Kb + 32 * 1024 + dk * 16);
            s0 = __builtin_amdgcn_mfma_f32_32x32x16_bf16(kf0, qf[dk], s0, 0, 0, 0);
            s1 = __builtin_amdgcn_mfma_f32_32x32x16_bf16(kf1, qf[dk], s1, 0, 0, 0);
        }

        // ---- softmax numerator (no max-sub), pack to bf16 pairs in-register
        unsigned int PK[2][8];
        float ps = 0.f;
        {
            float p[16];
#pragma unroll
            for (int i = 0; i < 16; ++i) { p[i] = __builtin_amdgcn_exp2f(s0[i]); ps += p[i]; }
#pragma unroll
            for (int j = 0; j < 8; ++j) PK[0][j] = pkbf2(p[2 * j], p[2 * j + 1]);
#pragma unroll
            for (int i = 0; i < 16; ++i) { p[i] = __builtin_amdgcn_exp2f(s1[i]); ps += p[i]; }
#pragma unroll
            for (int j = 0; j < 8; ++j) PK[1][j] = pkbf2(p[2 * j], p[2 * j + 1]);
        }
        l_run += ps;

        // ---- PV: P B-frag via shfl_xor(32)+select (R9-verified); V frags from L2
#pragma unroll
        for (int t = 0; t < 4; ++t) {
            const int bk = t >> 1, j0 = (t & 1) * 4;
            unsigned int A0 = PK[bk][j0],     C0 = PK[bk][j0 + 2];
            unsigned int A1 = PK[bk][j0 + 1], C1 = PK[bk][j0 + 3];
            unsigned int sA0 = (unsigned int)__shfl_xor((int)A0, 32, 64);
            unsigned int sC0 = (unsigned int)__shfl_xor((int)C0, 32, 64);
            unsigned int sA1 = (unsigned int)__shfl_xor((int)A1, 32, 64);
            unsigned int sC1 = (unsigned int)__shfl_xor((int)C1, 32, 64);
            union { unsigned int u[4]; s16x8 v; } pa;
            pa.u[0] = lh ? sC0 : A0;
            pa.u[1] = lh ? sC1 : A1;
            pa.u[2] = lh ? C0 : sA0;
            pa.u[3] = lh ? C1 : sA1;
            s16x8 vf0 = *(const s16x8*)(Vb + t * 16);
            s16x8 vf1 = *(const s16x8*)(Vb + 32 * 2048 + t * 16);
            oa[0] = __builtin_amdgcn_mfma_f32_32x32x16_bf16(vf0, pa.v, oa[0], 0, 0, 0);
            oa[1] = __builtin_amdgcn_mfma_f32_32x32x16_bf16(vf1, pa.v, oa[1], 0, 0, 0);
        }
    }

    // ---- merge: 4 quarter-partials, linear combine (LDS tree, 3 barriers)
    l_run += __shfl_xor(l_run, 32, 64);

    if (w >= 4) {
        int wrel = w - 4;
#pragma unroll
        for (int dh = 0; dh < 2; ++dh)
#pragma unroll
            for (int rg = 0; rg < 4; ++rg) {
                f32x4 c = { oa[dh][rg * 4 + 0], oa[dh][rg * 4 + 1],
                            oa[dh][rg * 4 + 2], oa[dh][rg * 4 + 3] };
                Xch[((wrel * 8 + dh * 4 + rg) << 6) + lane] = c;
            }
        if (lh == 0) Lx[wrel][q31] = l_run;
    }
    __syncthreads();
    if (w < 4) {
#pragma unroll
        for (int dh = 0; dh < 2; ++dh)
#pragma unroll
            for (int rg = 0; rg < 4; ++rg) {
                f32x4 po = Xch[((w * 8 + dh * 4 + rg) << 6) + lane];
                oa[dh][rg * 4 + 0] += po[0]; oa[dh][rg * 4 + 1] += po[1];
                oa[dh][rg * 4 + 2] += po[2]; oa[dh][rg * 4 + 3] += po[3];
            }
        l_run += Lx[w][q31];
    }
    __syncthreads();
    if (w == 2 || w == 3) {
        int wrel = w - 2;
#pragma unroll
        for (int dh = 0; dh < 2; ++dh)
#pragma unroll
            for (int rg = 0; rg < 4; ++rg) {
                f32x4 c = { oa[dh][rg * 4 + 0], oa[dh][rg * 4 + 1],
                            oa[dh][rg * 4 + 2], oa[dh][rg * 4 + 3] };
                Xch[((wrel * 8 + dh * 4 + rg) << 6) + lane] = c;
            }
        if (lh == 0) Lx[wrel][q31] = l_run;
    }
    __syncthreads();
    if (w < 2) {
        const float lt  = l_run + Lx[w][q31];
        const float inv = 1.0f / lt;
#pragma unroll
        for (int dh = 0; dh < 2; ++dh)
#pragma unroll
            for (int rg = 0; rg < 4; ++rg) {
                f32x4 po = Xch[((w * 8 + dh * 4 + rg) << 6) + lane];
                const int d0 = dh * 32 + rg * 8 + lh * 4;
                uint2 pw;
                pw.x = pkbf2((oa[dh][rg * 4 + 0] + po[0]) * inv,
                             (oa[dh][rg * 4 + 1] + po[1]) * inv);
                pw.y = pkbf2((oa[dh][rg * 4 + 2] + po[2]) * inv,
                             (oa[dh][rg * 4 + 3] + po[3]) * inv);
                *(uint2*)(O + qrow * 1024 + colbase + d0) = pw;
            }
    }
}

// ---------------- launch ----------------
extern "C" void kernel_launch(void* const* d_in, const int* in_sizes, int n_in,
                              void* d_out, int out_size, void* d_ws, size_t ws_size,
                              hipStream_t stream)
{
    const float* query = (const float*)d_in[0];
    const float* key   = (const float*)d_in[1];
    const float* value = (const float*)d_in[2];
    const float* Wq    = (const float*)d_in[3];
    const float* Wk    = (const float*)d_in[4];
    const float* Wv    = (const float*)d_in[5];
    const float* Wo    = (const float*)d_in[6];
    float* out = (float*)d_out;

    char* ws = (char*)d_ws;
    const size_t SZX = (size_t)4096 * 1024 * 2;  // 8 MiB
    const size_t SZW = (size_t)1024 * 1024 * 2;  // 2 MiB
    unsigned short* Xq  = (unsigned short*)(ws + 0);
    unsigned short* Xk  = (unsigned short*)(ws + SZX);
    unsigned short* Xv  = (unsigned short*)(ws + 2 * SZX);
    unsigned short* Wqb = (unsigned short*)(ws + 3 * SZX);
    unsigned short* Wkb = (unsigned short*)(ws + 3 * SZX + SZW);
    unsigned short* Wvb = (unsigned short*)(ws + 3 * SZX + 2 * SZW);
    unsigned short* Wob = (unsigned short*)(ws + 3 * SZX + 3 * SZW);
    unsigned short* Pq  = (unsigned short*)(ws + 3 * SZX + 4 * SZW);
    unsigned short* Pk  = (unsigned short*)(ws + 4 * SZX + 4 * SZW);
    unsigned short* Vt  = (unsigned short*)(ws + 5 * SZX + 4 * SZW);  // transposed V
    unsigned short* AO  = (unsigned short*)(ws + 6 * SZX + 4 * SZW);

    cvt_all<<<8192, 256, 0, stream>>>(query, key, value, Wq, Wk, Wv, Wo,
                                      Xq, Xk, Xv, Wqb, Wkb, Wvb, Wob);
    gemm_qkv<<<dim3(32, 8, 3), 512, 0, stream>>>(Xq, Xk, Xv, Wqb, Wkb, Wvb, Pq, Pk, Vt);
    attn9<<<1024, 512, 0, stream>>>(Pq, Pk, Vt, AO);
    gemm_out64<<<dim3(32, 16), 512, 0, stream>>>(AO, Wob, out);
}

// Round 19
// 120.754 us; speedup vs baseline: 3.8325x; 1.5724x over previous
//
#include <hip/hip_runtime.h>
#include <hip/hip_bf16.h>
#include <stdint.h>

typedef __attribute__((ext_vector_type(8))) short s16x8;
typedef __attribute__((ext_vector_type(4))) float f32x4;
typedef __attribute__((ext_vector_type(16))) float f32x16;

#define QSCALE 0.045084220027780106f  // (1/32) * log2(e), folded into Q projection

__device__ __forceinline__ unsigned short f2bf(float f) {
    union { float f; uint32_t u; } v; v.f = f;
    uint32_t u = v.u;
    u += 0x7FFFu + ((u >> 16) & 1u);   // round-to-nearest-even
    return (unsigned short)(u >> 16);
}

__device__ __forceinline__ unsigned int pkbf2(float a, float b) {
    union { __hip_bfloat162 h; unsigned int u; } x;
    x.h = __float22bfloat162_rn(float2{a, b});
    return x.u;
}

#define GLOAD_LDS16(gptr, lptr)                                                         \
    __builtin_amdgcn_global_load_lds(                                                   \
        (const __attribute__((address_space(1))) unsigned int*)(gptr),                  \
        (__attribute__((address_space(3))) unsigned int*)(lptr), 16, 0, 0)

// ---------------- fused fp32 -> bf16 conversion (all 7 tensors, 1 launch) ----------
__global__ __launch_bounds__(256)
void cvt_all(const float* __restrict__ q, const float* __restrict__ k,
             const float* __restrict__ v, const float* __restrict__ wq,
             const float* __restrict__ wk, const float* __restrict__ wv,
             const float* __restrict__ wo,
             unsigned short* __restrict__ xq, unsigned short* __restrict__ xk,
             unsigned short* __restrict__ xv, unsigned short* __restrict__ wqb,
             unsigned short* __restrict__ wkb, unsigned short* __restrict__ wvb,
             unsigned short* __restrict__ wob)
{
    int bid = blockIdx.x;
    const float* src; unsigned short* dst; int rel;
    if (bid < 6144) {
        int s = bid >> 11; rel = bid & 2047;
        src = (s == 0) ? q : (s == 1) ? k : v;
        dst = (s == 0) ? xq : (s == 1) ? xk : xv;
    } else {
        int s = (bid - 6144) >> 9; rel = (bid - 6144) & 511;
        src = (s == 0) ? wq : (s == 1) ? wk : (s == 2) ? wv : wo;
        dst = (s == 0) ? wqb : (s == 1) ? wkb : (s == 2) ? wvb : wob;
    }
    size_t i = (size_t)rel * 256 + threadIdx.x;
    const float4* p = (const float4*)src;
    float4 a = p[i * 2];
    float4 b2 = p[i * 2 + 1];
    s16x8 r;
    r[0] = (short)f2bf(a.x);  r[1] = (short)f2bf(a.y);
    r[2] = (short)f2bf(a.z);  r[3] = (short)f2bf(a.w);
    r[4] = (short)f2bf(b2.x); r[5] = (short)f2bf(b2.y);
    r[6] = (short)f2bf(b2.z); r[7] = (short)f2bf(b2.w);
    *(s16x8*)(dst + i * 8) = r;
}

// ---------------- NT GEMM, 512 threads / 8 waves (2M x 4N): C = A * Bt^T ------------
// mode 0: bf16 C (scaled); mode 1: f32 C; mode 2: Vt transposed write via LDS.
__device__ __forceinline__ void gemm_tile512(const unsigned short* __restrict__ A,
                                             const unsigned short* __restrict__ Bt,
                                             void* __restrict__ C,
                                             int N, int K, int mode, float cscale,
                                             unsigned short* Al, unsigned short* Bl,
                                             unsigned short* Tl)
{
    const int tid  = threadIdx.x;
    const int lane = tid & 63;
    const int w    = tid >> 6;          // 0..7
    const int wr   = w >> 2, wc = w & 3;
    const int l15  = lane & 15, l4 = lane >> 4;

    const int m0 = blockIdx.x * 128;
    const int n0 = blockIdx.y * 128;

    f32x4 acc[4][2];
#pragma unroll
    for (int i = 0; i < 4; ++i)
#pragma unroll
        for (int j = 0; j < 2; ++j) acc[i][j] = (f32x4){0.f, 0.f, 0.f, 0.f};

    const int slin = w * 64 + lane;
    const int srow = slin >> 2;
    const int scol = ((slin & 3) ^ ((srow >> 1) & 3)) * 8;

    int aoff[4], boff[2];
#pragma unroll
    for (int mi = 0; mi < 4; ++mi) {
        int rowa = wr * 64 + mi * 16 + l15;
        aoff[mi] = rowa * 32 + ((l4 ^ ((rowa >> 1) & 3)) * 8);
    }
#pragma unroll
    for (int nf = 0; nf < 2; ++nf) {
        int rowb = wc * 32 + nf * 16 + l15;
        boff[nf] = rowb * 32 + ((l4 ^ ((rowb >> 1) & 3)) * 8);
    }

    for (int k0 = 0; k0 < K; k0 += 32) {
        {
            const unsigned short* gA = A + (size_t)(m0 + srow) * K + k0 + scol;
            GLOAD_LDS16(gA, Al + w * 512);
            const unsigned short* gB = Bt + (size_t)(n0 + srow) * K + k0 + scol;
            GLOAD_LDS16(gB, Bl + w * 512);
        }
        __syncthreads();
        s16x8 af[4], bfr[2];
#pragma unroll
        for (int mi = 0; mi < 4; ++mi) af[mi] = *(const s16x8*)(Al + aoff[mi]);
#pragma unroll
        for (int nf = 0; nf < 2; ++nf) bfr[nf] = *(const s16x8*)(Bl + boff[nf]);
#pragma unroll
        for (int mi = 0; mi < 4; ++mi)
#pragma unroll
            for (int nf = 0; nf < 2; ++nf)
                acc[mi][nf] = __builtin_amdgcn_mfma_f32_16x16x32_bf16(af[mi], bfr[nf], acc[mi][nf], 0, 0, 0);
        __syncthreads();
    }

    if (mode == 2) {
        const int b_  = m0 >> 11;
        const int s0g = m0 & 2047;
#pragma unroll
        for (int c0 = 0; c0 < 128; c0 += 32) {
            if (wc == (c0 >> 5)) {
#pragma unroll
                for (int mi = 0; mi < 4; ++mi)
#pragma unroll
                    for (int nf = 0; nf < 2; ++nf) {
                        uint2 pw;
                        pw.x = pkbf2(acc[mi][nf][0], acc[mi][nf][1]);
                        pw.y = pkbf2(acc[mi][nf][2], acc[mi][nf][3]);
                        int c  = nf * 16 + l15;
                        int s4 = wr * 64 + mi * 16 + l4 * 4;
                        *(uint2*)&Tl[c * 136 + s4] = pw;
                    }
            }
            __syncthreads();
            {
                int d  = tid >> 4;          // 0..31
                int sg = tid & 15;
                s16x8 v = *(const s16x8*)&Tl[d * 136 + sg * 8];
                int colg  = n0 + c0 + d;
                int vtrow = (b_ * 16 + (colg >> 6)) * 64 + (colg & 63);
                *(s16x8*)((unsigned short*)C + (size_t)vtrow * 2048 + s0g + sg * 8) = v;
            }
            __syncthreads();
        }
        return;
    }

#pragma unroll
    for (int mi = 0; mi < 4; ++mi)
#pragma unroll
        for (int nf = 0; nf < 2; ++nf)
#pragma unroll
            for (int r = 0; r < 4; ++r) {
                int row = m0 + wr * 64 + mi * 16 + l4 * 4 + r;
                int col = n0 + wc * 32 + nf * 16 + l15;
                float v = acc[mi][nf][r];
                if (mode == 1) ((float*)C)[(size_t)row * N + col] = v;
                else           ((unsigned short*)C)[(size_t)row * N + col] = f2bf(v * cscale);
            }
}

__global__ __launch_bounds__(512, 6)
void gemm_qkv(const unsigned short* __restrict__ A0, const unsigned short* __restrict__ A1,
              const unsigned short* __restrict__ A2,
              const unsigned short* __restrict__ B0, const unsigned short* __restrict__ B1,
              const unsigned short* __restrict__ B2,
              unsigned short* __restrict__ C0, unsigned short* __restrict__ C1,
              unsigned short* __restrict__ C2)
{
    __shared__ unsigned short Al[128 * 32];
    __shared__ unsigned short Bl[128 * 32];
    __shared__ unsigned short Tl[32 * 136];
    int z = blockIdx.z;
    const unsigned short* A  = (z == 0) ? A0 : (z == 1) ? A1 : A2;
    const unsigned short* Bt = (z == 0) ? B0 : (z == 1) ? B1 : B2;
    unsigned short*       C  = (z == 0) ? C0 : (z == 1) ? C1 : C2;
    float cscale = (z == 0) ? QSCALE : 1.0f;
    int mode = (z == 2) ? 2 : 0;    // V projection writes Vt (transposed, coalesced)
    gemm_tile512(A, Bt, C, 1024, 1024, mode, cscale, Al, Bl, Tl);
}

// ---------------- gemm_out: 128x64 tiles, 2 blocks/CU (16 waves/CU) ----------------
__global__ __launch_bounds__(512, 4)
void gemm_out64(const unsigned short* __restrict__ A, const unsigned short* __restrict__ Bt,
                float* __restrict__ C)
{
    __shared__ unsigned short Al[128 * 32];   // 8 KB
    __shared__ unsigned short Bl[64 * 32];    // 4 KB

    const int tid  = threadIdx.x;
    const int lane = tid & 63;
    const int w    = tid >> 6;          // 0..7
    const int wr   = w >> 1, wc = w & 1;
    const int l15  = lane & 15, l4 = lane >> 4;

    const int m0 = blockIdx.x * 128;
    const int n0 = blockIdx.y * 64;
    const int N = 1024, K = 1024;

    f32x4 acc[2][2];
#pragma unroll
    for (int i = 0; i < 2; ++i)
#pragma unroll
        for (int j = 0; j < 2; ++j) acc[i][j] = (f32x4){0.f, 0.f, 0.f, 0.f};

    const int slin = w * 64 + lane;           // A: 512 granules
    const int srow = slin >> 2;
    const int scol = ((slin & 3) ^ ((srow >> 1) & 3)) * 8;
    const int brow = (w < 4) ? (slin >> 2) : 0;   // B: 256 granules (waves 0-3)
    const int bcol = ((slin & 3) ^ ((brow >> 1) & 3)) * 8;

    int aoff[2], boff[2];
#pragma unroll
    for (int mi = 0; mi < 2; ++mi) {
        int rowa = wr * 32 + mi * 16 + l15;
        aoff[mi] = rowa * 32 + ((l4 ^ ((rowa >> 1) & 3)) * 8);
    }
#pragma unroll
    for (int nf = 0; nf < 2; ++nf) {
        int rowb = wc * 32 + nf * 16 + l15;
        boff[nf] = rowb * 32 + ((l4 ^ ((rowb >> 1) & 3)) * 8);
    }

    for (int k0 = 0; k0 < K; k0 += 32) {
        {
            const unsigned short* gA = A + (size_t)(m0 + srow) * K + k0 + scol;
            GLOAD_LDS16(gA, Al + w * 512);
            if (w < 4) {
                const unsigned short* gB = Bt + (size_t)(n0 + brow) * K + k0 + bcol;
                GLOAD_LDS16(gB, Bl + w * 512);
            }
        }
        __syncthreads();
        s16x8 af[2], bfr[2];
#pragma unroll
        for (int mi = 0; mi < 2; ++mi) af[mi] = *(const s16x8*)(Al + aoff[mi]);
#pragma unroll
        for (int nf = 0; nf < 2; ++nf) bfr[nf] = *(const s16x8*)(Bl + boff[nf]);
#pragma unroll
        for (int mi = 0; mi < 2; ++mi)
#pragma unroll
            for (int nf = 0; nf < 2; ++nf)
                acc[mi][nf] = __builtin_amdgcn_mfma_f32_16x16x32_bf16(af[mi], bfr[nf], acc[mi][nf], 0, 0, 0);
        __syncthreads();
    }

#pragma unroll
    for (int mi = 0; mi < 2; ++mi)
#pragma unroll
        for (int nf = 0; nf < 2; ++nf)
#pragma unroll
            for (int r = 0; r < 4; ++r) {
                int row = m0 + wr * 32 + mi * 16 + l4 * 4 + r;
                int col = n0 + wc * 32 + nf * 16 + l15;
                C[(size_t)row * N + col] = acc[mi][nf][r];
            }
}

// ---------------- flash attention v8 (R12-verified, 56.7 us): LDS-staged, 32x32 -----
// 512 blocks x 512 threads, KV-split halves. 32x32x16 MFMA, in-register P hand-off.
__global__ __launch_bounds__(512, 4)
void attn8(const unsigned short* __restrict__ Q,
           const unsigned short* __restrict__ Kp,
           const unsigned short* __restrict__ Vt,
           unsigned short* __restrict__ O)
{
    __shared__ unsigned short Kl[2][2][64 * 64];   // [half][dbuf][key][d]
    __shared__ unsigned short Vl[2][2][64 * 64];   // [half][dbuf][d][key]

    const int tid  = threadIdx.x;
    const int lane = tid & 63;
    const int w    = tid >> 6;
    const int half = w >> 2, ws = w & 3;
    const int q31  = lane & 31;
    const int lh   = lane >> 5;
    const int m7q  = q31 & 7;
    const int j2   = ((q31 >> 3) & 3) << 1;

    const int hw  = blockIdx.x;
    const int xcd = hw & 7;
    const int idx = hw >> 3;
    const int bh  = xcd * 4 + (idx >> 4);
    const int qt  = idx & 15;
    const int b = bh >> 4, hd = bh & 15;
    const int colbase = hd * 64;
    const int kvbase = half * 1024;

    const size_t qrow = (size_t)(b * 2048 + qt * 128 + ws * 32 + q31);
    s16x8 qf[4];
#pragma unroll
    for (int dk = 0; dk < 4; ++dk)
        qf[dk] = *(const s16x8*)(Q + qrow * 1024 + colbase + dk * 16 + lh * 8);

    int krow[2], kcol[2];
#pragma unroll
    for (int i = 0; i < 2; ++i) {
        int lin = (i * 4 + ws) * 64 + lane;
        krow[i] = lin >> 3;
        int u   = lin & 7;
        kcol[i] = ((u ^ (krow[i] & 7) ^ (((krow[i] >> 3) & 3) << 1)) * 8);
    }

    f32x16 oa[2] = {};
    float l_run = 0.f;

#define STAGE_KV(buf, kv0)                                                                     \
    {                                                                                          \
        _Pragma("unroll")                                                                      \
        for (int i = 0; i < 2; ++i) {                                                          \
            const unsigned short* gk = Kp + (size_t)(b * 2048 + (kv0) + krow[i]) * 1024        \
                                          + colbase + kcol[i];                                 \
            GLOAD_LDS16(gk, &Kl[half][buf][(i * 4 + ws) * 512]);                               \
            const unsigned short* gv = Vt + ((size_t)bh * 64 + krow[i]) * 2048                 \
                                          + (kv0) + kcol[i];                                   \
            GLOAD_LDS16(gv, &Vl[half][buf][(i * 4 + ws) * 512]);                               \
        }                                                                                      \
    }

    STAGE_KV(0, kvbase);
    __syncthreads();

    for (int kt = 0; kt < 16; ++kt) {
        const int cur = kt & 1;
        if (kt < 15) STAGE_KV(cur ^ 1, kvbase + (kt + 1) * 64);

        // ---- QK^T: S^T[key][q]
        f32x16 s0 = {}, s1 = {};
#pragma unroll
        for (int dk = 0; dk < 4; ++dk) {
            const int sl = (((dk * 2 + lh) ^ m7q ^ j2) * 8);
            s16x8 kf0 = *(const s16x8*)(&Kl[half][cur][q31 * 64 + sl]);
            s16x8 kf1 = *(const s16x8*)(&Kl[half][cur][(32 + q31) * 64 + sl]);
            s0 = __builtin_amdgcn_mfma_f32_32x32x16_bf16(kf0, qf[dk], s0, 0, 0, 0);
            s1 = __builtin_amdgcn_mfma_f32_32x32x16_bf16(kf1, qf[dk], s1, 0, 0, 0);
        }

        // ---- softmax numerator (no max-sub), pack to bf16 pairs in-register
        unsigned int PK[2][8];
        float ps = 0.f;
        {
            float p[16];
#pragma unroll
            for (int i = 0; i < 16; ++i) { p[i] = __builtin_amdgcn_exp2f(s0[i]); ps += p[i]; }
#pragma unroll
            for (int j = 0; j < 8; ++j) PK[0][j] = pkbf2(p[2 * j], p[2 * j + 1]);
#pragma unroll
            for (int i = 0; i < 16; ++i) { p[i] = __builtin_amdgcn_exp2f(s1[i]); ps += p[i]; }
#pragma unroll
            for (int j = 0; j < 8; ++j) PK[1][j] = pkbf2(p[2 * j], p[2 * j + 1]);
        }
        l_run += ps;

        // ---- PV: P B-frag via shfl_xor(32)+select (R9-verified)
#pragma unroll
        for (int t = 0; t < 4; ++t) {
            const int bk = t >> 1, j0 = (t & 1) * 4;
            unsigned int A0 = PK[bk][j0],     C0 = PK[bk][j0 + 2];
            unsigned int A1 = PK[bk][j0 + 1], C1 = PK[bk][j0 + 3];
            unsigned int sA0 = (unsigned int)__shfl_xor((int)A0, 32, 64);
            unsigned int sC0 = (unsigned int)__shfl_xor((int)C0, 32, 64);
            unsigned int sA1 = (unsigned int)__shfl_xor((int)A1, 32, 64);
            unsigned int sC1 = (unsigned int)__shfl_xor((int)C1, 32, 64);
            union { unsigned int u[4]; s16x8 v; } pa;
            pa.u[0] = lh ? sC0 : A0;
            pa.u[1] = lh ? sC1 : A1;
            pa.u[2] = lh ? C0 : sA0;
            pa.u[3] = lh ? C1 : sA1;
            const int slv = (((t * 2 + lh) ^ m7q ^ j2) * 8);
            s16x8 vf0 = *(const s16x8*)(&Vl[half][cur][q31 * 64 + slv]);
            s16x8 vf1 = *(const s16x8*)(&Vl[half][cur][(32 + q31) * 64 + slv]);
            oa[0] = __builtin_amdgcn_mfma_f32_32x32x16_bf16(vf0, pa.v, oa[0], 0, 0, 0);
            oa[1] = __builtin_amdgcn_mfma_f32_32x32x16_bf16(vf1, pa.v, oa[1], 0, 0, 0);
        }
        __syncthreads();
    }

    l_run += __shfl_xor(l_run, 32, 64);

    f32x4* Xch = (f32x4*)&Kl[0][0][0];
    float*  Lx = (float*)&Vl[0][0][0];

    if (half == 1) {
#pragma unroll
        for (int dh = 0; dh < 2; ++dh)
#pragma unroll
            for (int rg = 0; rg < 4; ++rg) {
                f32x4 c = { oa[dh][rg * 4 + 0], oa[dh][rg * 4 + 1],
                            oa[dh][rg * 4 + 2], oa[dh][rg * 4 + 3] };
                Xch[((ws * 8 + dh * 4 + rg) << 6) + lane] = c;
            }
        if (lh == 0) Lx[ws * 32 + q31] = l_run;
    }
    __syncthreads();
    if (half == 0) {
        const float lt  = l_run + Lx[ws * 32 + q31];
        const float inv = 1.0f / lt;
#pragma unroll
        for (int dh = 0; dh < 2; ++dh)
#pragma unroll
            for (int rg = 0; rg < 4; ++rg) {
                f32x4 po = Xch[((ws * 8 + dh * 4 + rg) << 6) + lane];
                const int d0 = dh * 32 + rg * 8 + lh * 4;
                uint2 pw;
                pw.x = pkbf2((oa[dh][rg * 4 + 0] + po[0]) * inv,
                             (oa[dh][rg * 4 + 1] + po[1]) * inv);
                pw.y = pkbf2((oa[dh][rg * 4 + 2] + po[2]) * inv,
                             (oa[dh][rg * 4 + 3] + po[3]) * inv);
                *(uint2*)(O + qrow * 1024 + colbase + d0) = pw;
            }
    }
#undef STAGE_KV
}

// ---------------- launch ----------------
extern "C" void kernel_launch(void* const* d_in, const int* in_sizes, int n_in,
                              void* d_out, int out_size, void* d_ws, size_t ws_size,
                              hipStream_t stream)
{
    const float* query = (const float*)d_in[0];
    const float* key   = (const float*)d_in[1];
    const float* value = (const float*)d_in[2];
    const float* Wq    = (const float*)d_in[3];
    const float* Wk    = (const float*)d_in[4];
    const float* Wv    = (const float*)d_in[5];
    const float* Wo    = (const float*)d_in[6];
    float* out = (float*)d_out;

    char* ws = (char*)d_ws;
    const size_t SZX = (size_t)4096 * 1024 * 2;  // 8 MiB
    const size_t SZW = (size_t)1024 * 1024 * 2;  // 2 MiB
    unsigned short* Xq  = (unsigned short*)(ws + 0);
    unsigned short* Xk  = (unsigned short*)(ws + SZX);
    unsigned short* Xv  = (unsigned short*)(ws + 2 * SZX);
    unsigned short* Wqb = (unsigned short*)(ws + 3 * SZX);
    unsigned short* Wkb = (unsigned short*)(ws + 3 * SZX + SZW);
    unsigned short* Wvb = (unsigned short*)(ws + 3 * SZX + 2 * SZW);
    unsigned short* Wob = (unsigned short*)(ws + 3 * SZX + 3 * SZW);
    unsigned short* Pq  = (unsigned short*)(ws + 3 * SZX + 4 * SZW);
    unsigned short* Pk  = (unsigned short*)(ws + 4 * SZX + 4 * SZW);
    unsigned short* Vt  = (unsigned short*)(ws + 5 * SZX + 4 * SZW);  // transposed V
    unsigned short* AO  = (unsigned short*)(ws + 6 * SZX + 4 * SZW);

    cvt_all<<<8192, 256, 0, stream>>>(query, key, value, Wq, Wk, Wv, Wo,
                                      Xq, Xk, Xv, Wqb, Wkb, Wvb, Wob);
    gemm_qkv<<<dim3(32, 8, 3), 512, 0, stream>>>(Xq, Xk, Xv, Wqb, Wkb, Wvb, Pq, Pk, Vt);
    attn8<<<512, 512, 0, stream>>>(Pq, Pk, Vt, AO);
    gemm_out64<<<dim3(32, 16), 512, 0, stream>>>(AO, Wob, out);
}